// Round 1
// baseline (78.275 us; speedup 1.0000x reference)
//
#include <hip/hip_runtime.h>
#include <math.h>
#include <limits.h>

#define NCHUNK 16
#define PLACEHOLDER (-1)

// Combine (max, sum-of-exp-relative-to-max, argmax-index) pairs.
// Tie-break: lower index wins (matches jnp.argmax first-occurrence).
__device__ __forceinline__ void comb_ms(float& m, float& s, int& i,
                                        float m2, float s2, int i2) {
  if (m2 > m || (m2 == m && i2 < i)) {
    if (m2 > m) {
      s = (m == -INFINITY ? 0.f : s * expf(m - m2)) + s2;
      m = m2;
    } else {
      s += s2;
    }
    i = i2;
  } else {
    s += (m2 == -INFINITY) ? 0.f : s2 * expf(m2 - m);
  }
}

__device__ __forceinline__ void comb_mx(float& m, int& i, float m2, int i2) {
  if (m2 > m || (m2 == m && i2 < i)) { m = m2; i = i2; }
}

// Pass 1: per-(row, chunk) partial {max logit, sum exp, argmax idx}.
__global__ __launch_bounds__(256) void k_stats_partial(
    const float* __restrict__ logits, int V, int chunk_elems,
    float* __restrict__ pm, float* __restrict__ ps, int* __restrict__ pidx) {
  const int row = blockIdx.y;
  const int chunk = blockIdx.x;
  const int tid = threadIdx.x;
  const int begin = chunk * chunk_elems;
  const int end = min(begin + chunk_elems, V);

  float m = -INFINITY, ssum = 0.f;
  int mi = INT_MAX;
  const float* xrow = logits + (size_t)row * V;
  const float4* x4 = (const float4*)xrow;
  const int vbeg = begin >> 2;
  const int vend = end >> 2;
  for (int i = vbeg + tid; i < vend; i += 256) {
    float4 v = x4[i];
    const int gi = i << 2;
    float vals[4] = {v.x, v.y, v.z, v.w};
#pragma unroll
    for (int k = 0; k < 4; ++k) {
      float x = vals[k];
      if (x > m) {
        ssum = ssum * expf(m - x) + 1.f;
        m = x;
        mi = gi + k;
      } else {
        ssum += expf(x - m);
      }
    }
  }
  // scalar tail (only if V % 4 != 0)
  for (int j = (vend << 2) + tid; j < end; j += 256) {
    float x = xrow[j];
    if (x > m) { ssum = ssum * expf(m - x) + 1.f; m = x; mi = j; }
    else       { ssum += expf(x - m); }
  }

  for (int off = 32; off; off >>= 1) {
    float m2 = __shfl_xor(m, off);
    float s2 = __shfl_xor(ssum, off);
    int   i2 = __shfl_xor(mi, off);
    comb_ms(m, ssum, mi, m2, s2, i2);
  }
  __shared__ float lm[4], ls[4];
  __shared__ int li[4];
  const int wv = tid >> 6;
  if ((tid & 63) == 0) { lm[wv] = m; ls[wv] = ssum; li[wv] = mi; }
  __syncthreads();
  if (tid == 0) {
#pragma unroll
    for (int w = 1; w < 4; ++w) comb_ms(m, ssum, mi, lm[w], ls[w], li[w]);
    const int o = row * NCHUNK + chunk;
    pm[o] = m; ps[o] = ssum; pidx[o] = mi;
  }
}

// Reduce chunk partials per row; also compute the accept decision.
__global__ __launch_bounds__(64) void k_stats_reduce(
    const float* __restrict__ logits, const float* __restrict__ draft,
    const int* __restrict__ draft_ids, const float* __restrict__ uniform,
    const float* __restrict__ pm, const float* __restrict__ ps,
    const int* __restrict__ pidx, int V,
    float* __restrict__ rowM, float* __restrict__ rowZ,
    int* __restrict__ rowArgmax, int* __restrict__ rowAccept) {
  const int row = blockIdx.x;
  const int lane = threadIdx.x;
  float m = -INFINITY, ssum = 0.f;
  int mi = INT_MAX;
  if (lane < NCHUNK) {
    const int o = row * NCHUNK + lane;
    m = pm[o]; ssum = ps[o]; mi = pidx[o];
  }
  for (int off = 32; off; off >>= 1) {
    float m2 = __shfl_xor(m, off);
    float s2 = __shfl_xor(ssum, off);
    int   i2 = __shfl_xor(mi, off);
    comb_ms(m, ssum, mi, m2, s2, i2);
  }
  if (lane == 0) {
    rowM[row] = m; rowZ[row] = ssum; rowArgmax[row] = mi;
    const int tok = draft_ids[row];
    const float lat = logits[(size_t)row * V + tok];
    const float dat = draft[(size_t)row * V + tok];
    const float tat = expf(lat - m) / ssum;
    const float u = uniform[row];
    const float ratio = (dat > 0.f) ? (tat / dat) : 0.f;
    rowAccept[row] = (dat > 0.f && ratio >= u) ? 1 : 0;
  }
}

// Pass 2: per-(row, chunk) partial argmax of max(p - q, 0) * inv_q.
// Greedy rows (top_k == 1) early-out with a sentinel.
__global__ __launch_bounds__(256) void k_score_partial(
    const float* __restrict__ logits, const float* __restrict__ draft,
    const float* __restrict__ invq, const int* __restrict__ topk,
    const float* __restrict__ rowM, const float* __restrict__ rowZ,
    int V, int S, int chunk_elems,
    float* __restrict__ psm, int* __restrict__ psi) {
  const int row = blockIdx.y;
  const int chunk = blockIdx.x;
  const int tid = threadIdx.x;
  const int b = row / S;
  const int o = row * NCHUNK + chunk;
  if (topk[b] == 1) {
    if (tid == 0) { psm[o] = 0.f; psi[o] = 0; }
    return;
  }
  const float M = rowM[row];
  const float invZ = 1.0f / rowZ[row];
  const int begin = chunk * chunk_elems;
  const int end = min(begin + chunk_elems, V);

  float sm = -INFINITY;
  int si = INT_MAX;
  const float* lrow = logits + (size_t)row * V;
  const float* drow = draft + (size_t)row * V;
  const float* qrow = invq + (size_t)b * V;
  const float4* l4 = (const float4*)lrow;
  const float4* d4 = (const float4*)drow;
  const float4* q4 = (const float4*)qrow;
  const int vbeg = begin >> 2;
  const int vend = end >> 2;
  for (int i = vbeg + tid; i < vend; i += 256) {
    float4 lv = l4[i];
    float4 dv = d4[i];
    float4 qv = q4[i];
    const int gi = i << 2;
    float l[4] = {lv.x, lv.y, lv.z, lv.w};
    float d[4] = {dv.x, dv.y, dv.z, dv.w};
    float q[4] = {qv.x, qv.y, qv.z, qv.w};
#pragma unroll
    for (int k = 0; k < 4; ++k) {
      float p = expf(l[k] - M) * invZ;
      float sc = fmaxf(p - d[k], 0.f) * q[k];
      if (sc > sm) { sm = sc; si = gi + k; }
    }
  }
  // scalar tail (only if V % 4 != 0)
  for (int j = (vend << 2) + tid; j < end; j += 256) {
    float p = expf(lrow[j] - M) * invZ;
    float sc = fmaxf(p - drow[j], 0.f) * qrow[j];
    if (sc > sm) { sm = sc; si = j; }
  }

  for (int off = 32; off; off >>= 1) {
    float m2 = __shfl_xor(sm, off);
    int   i2 = __shfl_xor(si, off);
    comb_mx(sm, si, m2, i2);
  }
  __shared__ float lsm[4];
  __shared__ int lsi[4];
  const int wv = tid >> 6;
  if ((tid & 63) == 0) { lsm[wv] = sm; lsi[wv] = si; }
  __syncthreads();
  if (tid == 0) {
#pragma unroll
    for (int w = 1; w < 4; ++w) comb_mx(sm, si, lsm[w], lsi[w]);
    psm[o] = sm; psi[o] = si;
  }
}

// Finalize: one block per batch row b. Lanes reduce score partials
// (lane = s*16 + chunk), lane 0 does the S+1 prefix logic.
__global__ __launch_bounds__(64) void k_finalize(
    const int* __restrict__ draft_ids, const int* __restrict__ bonus,
    const int* __restrict__ topk,
    const int* __restrict__ rowArgmax, const int* __restrict__ rowAccept,
    const float* __restrict__ psm, const int* __restrict__ psi,
    int B, int S, int* __restrict__ out) {
  const int b = blockIdx.x;
  const int lane = threadIdx.x;
  const int s = lane >> 4;   // sequence position (requires S <= 4, NCHUNK == 16)
  const int c = lane & 15;   // chunk

  __shared__ int rec[8];
  float sm = -INFINITY;
  int si = INT_MAX;
  if (s < S) {
    const int o = (b * S + s) * NCHUNK + c;
    sm = psm[o]; si = psi[o];
  }
  for (int off = 8; off; off >>= 1) {
    float m2 = __shfl_xor(sm, off);
    int   i2 = __shfl_xor(si, off);
    comb_mx(sm, si, m2, i2);
  }
  if (c == 0 && s < S) rec[s] = si;
  __syncthreads();

  if (lane == 0) {
    const bool greedy = (topk[b] == 1);
    int tok[9];
    bool rejected_before = false, any_rej = false;
    for (int ss = 0; ss < S; ++ss) {
      const int row = b * S + ss;
      const int dtok = draft_ids[row];
      int t;
      bool rej;
      if (greedy) {
        const int ta = rowArgmax[row];
        rej = (dtok != ta);
        t = ta;
      } else {
        const int acc = rowAccept[row];
        rej = !acc;
        t = acc ? dtok : rec[ss];
      }
      tok[ss] = rejected_before ? PLACEHOLDER : t;
      any_rej = any_rej || rej;
      rejected_before = rejected_before || rej;
    }
    tok[S] = any_rej ? PLACEHOLDER : bonus[b];
    int na = 0;
    const int Sp1 = S + 1;
    for (int j = 0; j < Sp1; ++j) na += (tok[j] != PLACEHOLDER);
    for (int j = 0; j < Sp1; ++j) out[b * Sp1 + j] = tok[j];
    out[B * Sp1 + b] = Sp1 - na;             // num_rejected_tokens
    out[B * Sp1 + B + b] = tok[na - 1];      // last_token_ids
  }
}

extern "C" void kernel_launch(void* const* d_in, const int* in_sizes, int n_in,
                              void* d_out, int out_size, void* d_ws, size_t ws_size,
                              hipStream_t stream) {
  const float* logits = (const float*)d_in[0];
  const float* draft  = (const float*)d_in[1];
  const int*   dids   = (const int*)d_in[2];
  const int*   bonus  = (const int*)d_in[3];
  const int*   topk   = (const int*)d_in[4];
  const float* unif   = (const float*)d_in[5];
  const float* invq   = (const float*)d_in[6];
  int* out = (int*)d_out;

  const int B = in_sizes[3];
  const int S = in_sizes[2] / B;
  const int V = in_sizes[0] / in_sizes[2];
  const int nrows = B * S;

  char* w = (char*)d_ws;
  float* pm   = (float*)w; w += (size_t)nrows * NCHUNK * sizeof(float);
  float* ps   = (float*)w; w += (size_t)nrows * NCHUNK * sizeof(float);
  int*   pidx = (int*)w;   w += (size_t)nrows * NCHUNK * sizeof(int);
  float* psm  = (float*)w; w += (size_t)nrows * NCHUNK * sizeof(float);
  int*   psi  = (int*)w;   w += (size_t)nrows * NCHUNK * sizeof(int);
  float* rowM = (float*)w; w += (size_t)nrows * sizeof(float);
  float* rowZ = (float*)w; w += (size_t)nrows * sizeof(float);
  int* rowArgmax = (int*)w; w += (size_t)nrows * sizeof(int);
  int* rowAccept = (int*)w; w += (size_t)nrows * sizeof(int);

  int chunk_elems = (V + NCHUNK - 1) / NCHUNK;
  chunk_elems = (chunk_elems + 3) & ~3;  // keep float4 alignment per chunk

  dim3 grid1(NCHUNK, nrows);
  k_stats_partial<<<grid1, dim3(256), 0, stream>>>(logits, V, chunk_elems,
                                                   pm, ps, pidx);
  k_stats_reduce<<<dim3(nrows), dim3(64), 0, stream>>>(
      logits, draft, dids, unif, pm, ps, pidx, V,
      rowM, rowZ, rowArgmax, rowAccept);
  k_score_partial<<<grid1, dim3(256), 0, stream>>>(
      logits, draft, invq, topk, rowM, rowZ, V, S, chunk_elems, psm, psi);
  k_finalize<<<dim3(B), dim3(64), 0, stream>>>(
      dids, bonus, topk, rowArgmax, rowAccept, psm, psi, B, S, out);
}